// Round 11
// baseline (511.707 us; speedup 1.0000x reference)
//
#include <hip/hip_runtime.h>

// GCN forward: l2norm -> [GEMM -> SpMM -> ReLU] x3 (last layer no ReLU)
// CSR built on-device (histogram + hierarchical scan + 4-pass row-range scatter:
// each pass's destination region (~3.2MB) fits per-XCD L2, killing the 8x
// write amplification of single-pass random scatter).
// GEMMs on bf16 MFMA (16x16x32, fp32 accum), global_load_lds staging with
// pre-swizzled source. X, H, T, W bf16; SpMM accumulates fp32; output fp32.

constexpr int IN_DIM = 256, HD1 = 128, HD2 = 64, OUT_DIM = 32;
constexpr int SCAN_CHUNK = 2048;
constexpr int SCATTER_PASSES = 4;

typedef __bf16 bf16x8 __attribute__((ext_vector_type(8)));
typedef float f32x4 __attribute__((ext_vector_type(4)));

__device__ inline ushort f32_to_bf16(float x) {
    unsigned u = __float_as_uint(x);
    unsigned r = (u + 0x7fff + ((u >> 16) & 1)) >> 16;  // round-nearest-even
    return (ushort)r;
}

__device__ inline void unpack_bf16x2(unsigned u, float& lo, float& hi) {
    lo = __uint_as_float(u << 16);
    hi = __uint_as_float(u & 0xffff0000u);
}

// ---------------- L2 normalize -> bf16 X (one wave per row) ----------------
__global__ __launch_bounds__(256) void l2norm_kernel(const float* __restrict__ in,
                                                     ushort* __restrict__ out, int M) {
    int wave = threadIdx.x >> 6;
    int lane = threadIdx.x & 63;
    int row = blockIdx.x * 4 + wave;
    if (row >= M) return;
    const float4 v = *reinterpret_cast<const float4*>(&in[(size_t)row * IN_DIM + lane * 4]);
    float s = v.x * v.x + v.y * v.y + v.z * v.z + v.w * v.w;
    #pragma unroll
    for (int off = 32; off; off >>= 1) s += __shfl_xor(s, off, 64);
    float scale = 1.0f / sqrtf(fmaxf(s, 1e-12f));
    uint2 pk;
    pk.x = (unsigned)f32_to_bf16(v.x * scale) | ((unsigned)f32_to_bf16(v.y * scale) << 16);
    pk.y = (unsigned)f32_to_bf16(v.z * scale) | ((unsigned)f32_to_bf16(v.w * scale) << 16);
    *reinterpret_cast<uint2*>(&out[(size_t)row * IN_DIM + lane * 4]) = pk;
}

// ---------------- weight transpose + bf16: WT[n][k] = W[k][n] ----------------
__global__ __launch_bounds__(256) void wt_kernel(const float* __restrict__ W,
                                                 ushort* __restrict__ WT, int K, int N) {
    int idx = blockIdx.x * 256 + threadIdx.x;
    if (idx < K * N) {
        int k = idx / N, n = idx % N;
        WT[(size_t)n * K + k] = f32_to_bf16(W[idx]);
    }
}

// ---------------- CSR build ----------------
__global__ __launch_bounds__(256) void hist_kernel(const int* __restrict__ row,
                                                   int* __restrict__ counts, int E) {
    int e = blockIdx.x * blockDim.x + threadIdx.x;
    if (e < E) atomicAdd(&counts[row[e]], 1);
}

__global__ __launch_bounds__(256) void scan_partial(const int* __restrict__ counts,
                                                    int* __restrict__ bsum, int n) {
    __shared__ int sm[256];
    const int tid = threadIdx.x;
    const int base = blockIdx.x * SCAN_CHUNK + tid * 8;
    int s = 0;
    #pragma unroll
    for (int i = 0; i < 8; ++i) {
        int idx = base + i;
        if (idx < n) s += counts[idx];
    }
    sm[tid] = s;
    __syncthreads();
    #pragma unroll
    for (int off = 128; off; off >>= 1) {
        if (tid < off) sm[tid] += sm[tid + off];
        __syncthreads();
    }
    if (tid == 0) bsum[blockIdx.x] = sm[0];
}

__global__ __launch_bounds__(256) void scan_blocksums(const int* __restrict__ bsum,
                                                      int* __restrict__ boff, int nblk) {
    __shared__ int sm[256];
    const int tid = threadIdx.x;
    int v = (tid < nblk) ? bsum[tid] : 0;
    sm[tid] = v;
    __syncthreads();
    #pragma unroll
    for (int off = 1; off < 256; off <<= 1) {
        int t = (tid >= off) ? sm[tid - off] : 0;
        __syncthreads();
        sm[tid] += t;
        __syncthreads();
    }
    if (tid < nblk) boff[tid] = sm[tid] - v;
    if (tid == 255) boff[nblk] = sm[255];
}

__global__ __launch_bounds__(256) void scan_final(const int* __restrict__ counts,
                                                  const int* __restrict__ boff,
                                                  int* __restrict__ row_ptr, int n, int nblk) {
    __shared__ int sm[256];
    const int tid = threadIdx.x;
    const int base = blockIdx.x * SCAN_CHUNK + tid * 8;
    int c[8];
    int s = 0;
    #pragma unroll
    for (int i = 0; i < 8; ++i) {
        int idx = base + i;
        c[i] = (idx < n) ? counts[idx] : 0;
        s += c[i];
    }
    sm[tid] = s;
    __syncthreads();
    #pragma unroll
    for (int off = 1; off < 256; off <<= 1) {
        int t = (tid >= off) ? sm[tid - off] : 0;
        __syncthreads();
        sm[tid] += t;
        __syncthreads();
    }
    int run = boff[blockIdx.x] + sm[tid] - s;
    #pragma unroll
    for (int i = 0; i < 8; ++i) {
        int idx = base + i;
        if (idx < n) row_ptr[idx] = run;
        run += c[i];
    }
    if (blockIdx.x == 0 && tid == 0) row_ptr[n] = boff[nblk];
}

// row-range scatter: only edges with r in [r0,r1) are written this pass,
// so the destination region fits in per-XCD L2 (no write amplification).
__global__ __launch_bounds__(256) void scatter_kernel(const int* __restrict__ row,
                                                      const int* __restrict__ col,
                                                      const float* __restrict__ val,
                                                      const int* __restrict__ row_ptr,
                                                      int* __restrict__ row_cur,
                                                      int2* __restrict__ pairs, int E,
                                                      int r0, int r1) {
    int e = blockIdx.x * blockDim.x + threadIdx.x;
    if (e < E) {
        int r = row[e];
        if (r >= r0 && r < r1) {
            int pos = row_ptr[r] + atomicAdd(&row_cur[r], 1);
            pairs[pos] = make_int2(col[e], __float_as_int(val[e]));
        }
    }
}

// ---------------- bf16 MFMA GEMM: C[Mp,BN] = A[Mp,K] @ BT[BN,K]^T ----------------
// BM=128 rows/block, BK=64, 4 waves (WM x WN). LDS rows are 128B (64 bf16) with
// XOR swizzle ((row&7)<<4) applied on the GLOBAL source (staging) and on ds_read.
template <int BN, int WM, int WN>
__global__ __launch_bounds__(256) void gemm_bf16_mfma(
    const ushort* __restrict__ A, const ushort* __restrict__ BT,
    ushort* __restrict__ C, int K) {
    constexpr int BM = 128, BK = 64;
    constexpr int FM = BM / WM / 16;
    constexpr int FN = BN / WN / 16;
    __shared__ ushort As[BM * BK];
    __shared__ ushort Bs[BN * BK];
    const int tid = threadIdx.x;
    const int lane = tid & 63;
    const int wid = tid >> 6;
    const int wm = wid / WN;
    const int wn = wid % WN;
    const int row0 = blockIdx.x * BM;
    const size_t strideB = (size_t)K * 2;  // bytes per row of A and BT

    f32x4 acc[FM][FN] = {};

    // reader lane offset within a 16-row x 64-col subtile (bytes), swizzled
    const int lkb = ((lane >> 4) << 4) ^ ((lane & 7) << 4);
    const int laneOff = (lane & 15) * 128 + lkb;

    for (int k0 = 0; k0 < K; k0 += BK) {
        // ---- stage A tile (BM rows) ----
        {
            constexpr int per_wave = BM * 128 / 4;
            const char* gbase = (const char*)(A + (size_t)row0 * K);
            #pragma unroll
            for (int i = 0; i < per_wave / 1024; ++i) {
                int o = wid * per_wave + i * 1024 + lane * 16;
                int row = o >> 7;
                int kb = (o & 127) ^ ((row & 7) << 4);
                const char* src = gbase + (size_t)row * strideB + (size_t)k0 * 2 + kb;
                ushort* dst = As + (wid * per_wave + i * 1024) / 2;
                __builtin_amdgcn_global_load_lds(
                    (const __attribute__((address_space(1))) unsigned int*)src,
                    (__attribute__((address_space(3))) unsigned int*)dst, 16, 0, 0);
            }
        }
        // ---- stage B tile (BN rows) ----
        {
            constexpr int per_wave = BN * 128 / 4;
            const char* gbase = (const char*)BT;
            #pragma unroll
            for (int i = 0; i < per_wave / 1024; ++i) {
                int o = wid * per_wave + i * 1024 + lane * 16;
                int row = o >> 7;
                int kb = (o & 127) ^ ((row & 7) << 4);
                const char* src = gbase + (size_t)row * strideB + (size_t)k0 * 2 + kb;
                ushort* dst = Bs + (wid * per_wave + i * 1024) / 2;
                __builtin_amdgcn_global_load_lds(
                    (const __attribute__((address_space(1))) unsigned int*)src,
                    (__attribute__((address_space(3))) unsigned int*)dst, 16, 0, 0);
            }
        }
        __syncthreads();

        #pragma unroll
        for (int w = 0; w < BK / 32; ++w) {
            bf16x8 af[FM], bfr[FN];
            #pragma unroll
            for (int mi = 0; mi < FM; ++mi) {
                int byte = wm * FM * 2048 + mi * 2048 + (laneOff ^ (w << 6));
                af[mi] = *(const bf16x8*)((const char*)As + byte);
            }
            #pragma unroll
            for (int ni = 0; ni < FN; ++ni) {
                int byte = wn * FN * 2048 + ni * 2048 + (laneOff ^ (w << 6));
                bfr[ni] = *(const bf16x8*)((const char*)Bs + byte);
            }
            #pragma unroll
            for (int mi = 0; mi < FM; ++mi)
                #pragma unroll
                for (int ni = 0; ni < FN; ++ni)
                    acc[mi][ni] = __builtin_amdgcn_mfma_f32_16x16x32_bf16(
                        af[mi], bfr[ni], acc[mi][ni], 0, 0, 0);
        }
        __syncthreads();
    }

    // ---- store C (bf16), C/D layout: col=lane&15, row=(lane>>4)*4+r ----
    #pragma unroll
    for (int mi = 0; mi < FM; ++mi) {
        #pragma unroll
        for (int ni = 0; ni < FN; ++ni) {
            int rbase = row0 + wm * FM * 16 + mi * 16 + ((lane >> 4) << 2);
            int col = wn * FN * 16 + ni * 16 + (lane & 15);
            #pragma unroll
            for (int r = 0; r < 4; ++r)
                C[(size_t)(rbase + r) * BN + col] = f32_to_bf16(acc[mi][ni][r]);
        }
    }
}

// ---------------- CSR SpMM, bf16 gather: out[r,:] = sum_j val_j * H[col_j,:] ----------------
template <int D, bool RELU, bool OUTF32>
__global__ __launch_bounds__(256) void spmm_bf16(const int* __restrict__ row_ptr,
                                                 const int2* __restrict__ pairs,
                                                 const ushort* __restrict__ H,
                                                 void* __restrict__ outp, int M) {
    constexpr int TPR = D / 8;                 // threads per row, 8 bf16 (16B) per lane
    const int rpb = 256 / TPR;
    const int lg = threadIdx.x % TPR;
    const int rloc = threadIdx.x / TPR;
    int r = blockIdx.x * rpb + rloc;
    if (r >= M) return;
    const int jb = row_ptr[r], je = row_ptr[r + 1];
    float acc[8] = {};
    int j = jb;
    for (; j + 1 < je; j += 2) {               // two independent gathers in flight
        int2 p0 = pairs[j];
        int2 p1 = pairs[j + 1];
        uint4 u0 = *reinterpret_cast<const uint4*>(&H[(size_t)p0.x * D + lg * 8]);
        uint4 u1 = *reinterpret_cast<const uint4*>(&H[(size_t)p1.x * D + lg * 8]);
        float v0 = __int_as_float(p0.y), v1 = __int_as_float(p1.y);
        float f[8];
        unpack_bf16x2(u0.x, f[0], f[1]); unpack_bf16x2(u0.y, f[2], f[3]);
        unpack_bf16x2(u0.z, f[4], f[5]); unpack_bf16x2(u0.w, f[6], f[7]);
        #pragma unroll
        for (int i = 0; i < 8; ++i) acc[i] = fmaf(v0, f[i], acc[i]);
        unpack_bf16x2(u1.x, f[0], f[1]); unpack_bf16x2(u1.y, f[2], f[3]);
        unpack_bf16x2(u1.z, f[4], f[5]); unpack_bf16x2(u1.w, f[6], f[7]);
        #pragma unroll
        for (int i = 0; i < 8; ++i) acc[i] = fmaf(v1, f[i], acc[i]);
    }
    if (j < je) {
        int2 p0 = pairs[j];
        uint4 u0 = *reinterpret_cast<const uint4*>(&H[(size_t)p0.x * D + lg * 8]);
        float v0 = __int_as_float(p0.y);
        float f[8];
        unpack_bf16x2(u0.x, f[0], f[1]); unpack_bf16x2(u0.y, f[2], f[3]);
        unpack_bf16x2(u0.z, f[4], f[5]); unpack_bf16x2(u0.w, f[6], f[7]);
        #pragma unroll
        for (int i = 0; i < 8; ++i) acc[i] = fmaf(v0, f[i], acc[i]);
    }
    if (RELU) {
        #pragma unroll
        for (int i = 0; i < 8; ++i) acc[i] = fmaxf(acc[i], 0.f);
    }
    if (OUTF32) {
        float* dst = (float*)outp + (size_t)r * D + lg * 8;
        *reinterpret_cast<float4*>(dst) = *reinterpret_cast<const float4*>(&acc[0]);
        *reinterpret_cast<float4*>(dst + 4) = *reinterpret_cast<const float4*>(&acc[4]);
    } else {
        uint4 pk;
        pk.x = (unsigned)f32_to_bf16(acc[0]) | ((unsigned)f32_to_bf16(acc[1]) << 16);
        pk.y = (unsigned)f32_to_bf16(acc[2]) | ((unsigned)f32_to_bf16(acc[3]) << 16);
        pk.z = (unsigned)f32_to_bf16(acc[4]) | ((unsigned)f32_to_bf16(acc[5]) << 16);
        pk.w = (unsigned)f32_to_bf16(acc[6]) | ((unsigned)f32_to_bf16(acc[7]) << 16);
        *reinterpret_cast<uint4*>((ushort*)outp + (size_t)r * D + lg * 8) = pk;
    }
}

extern "C" void kernel_launch(void* const* d_in, const int* in_sizes, int n_in,
                              void* d_out, int out_size, void* d_ws, size_t ws_size,
                              hipStream_t stream) {
    const float* features  = (const float*)d_in[0];
    const float* edge_vals = (const float*)d_in[1];
    const float* W0        = (const float*)d_in[2];
    const float* W1        = (const float*)d_in[3];
    const float* W2        = (const float*)d_in[4];
    const int*   edge_row  = (const int*)d_in[5];
    const int*   edge_col  = (const int*)d_in[6];
    const int M = in_sizes[0] / IN_DIM;     // 100000
    const int E = in_sizes[1];              // 1600000
    const int Mp = ((M + 127) / 128) * 128; // 100096, padded for GEMM tiles

    char* ws = (char*)d_ws;
    size_t o = 0;
    auto alloc = [&](size_t bytes) {
        size_t r = o;
        o += (bytes + 1023) & ~(size_t)1023;
        return r;
    };
    ushort* XH    = (ushort*)(ws + alloc((size_t)Mp * IN_DIM * 2));  // X, then reused as H
    ushort* T     = (ushort*)(ws + alloc((size_t)Mp * HD1 * 2));     // GEMM outputs (bf16)
    size_t counts_off = alloc((size_t)M * 4);
    int*   counts = (int*)(ws + counts_off);
    int*   rowcur = (int*)(ws + alloc((size_t)M * 4));
    size_t rowptr_off = alloc((size_t)(M + 1) * 4);
    int*   rowptr = (int*)(ws + rowptr_off);
    int2*  pairs  = (int2*)(ws + alloc((size_t)E * 8));
    const int nblk_scan = (M + SCAN_CHUNK - 1) / SCAN_CHUNK;
    int*   bsum   = (int*)(ws + alloc((size_t)256 * 4));
    int*   boff   = (int*)(ws + alloc((size_t)257 * 4));
    ushort* W0T   = (ushort*)(ws + alloc((size_t)HD1 * IN_DIM * 2));
    ushort* W1T   = (ushort*)(ws + alloc((size_t)HD2 * HD1 * 2));
    ushort* W2T   = (ushort*)(ws + alloc((size_t)OUT_DIM * HD2 * 2));
    float* out = (float*)d_out;
    (void)ws_size; (void)n_in; (void)out_size;

    hipMemsetAsync(ws + counts_off, 0, rowptr_off - counts_off, stream);

    // CSR build
    hist_kernel<<<(E + 255) / 256, 256, 0, stream>>>(edge_row, counts, E);
    scan_partial<<<nblk_scan, 256, 0, stream>>>(counts, bsum, M);
    scan_blocksums<<<1, 256, 0, stream>>>(bsum, boff, nblk_scan);
    scan_final<<<nblk_scan, 256, 0, stream>>>(counts, boff, rowptr, M, nblk_scan);
    // 4-pass row-range scatter: each pass's pairs region (~3.2MB) fits per-XCD L2
    {
        const int chunk = (M + SCATTER_PASSES - 1) / SCATTER_PASSES;
        for (int p = 0; p < SCATTER_PASSES; ++p) {
            int r0 = p * chunk;
            int r1 = min(M, r0 + chunk);
            scatter_kernel<<<(E + 255) / 256, 256, 0, stream>>>(
                edge_row, edge_col, edge_vals, rowptr, rowcur, pairs, E, r0, r1);
        }
    }

    // weights -> bf16 transposed
    wt_kernel<<<(IN_DIM * HD1 + 255) / 256, 256, 0, stream>>>(W0, W0T, IN_DIM, HD1);
    wt_kernel<<<(HD1 * HD2 + 255) / 256, 256, 0, stream>>>(W1, W1T, HD1, HD2);
    wt_kernel<<<(HD2 * OUT_DIM + 255) / 256, 256, 0, stream>>>(W2, W2T, HD2, OUT_DIM);

    // normalize -> bf16 X
    l2norm_kernel<<<(M + 3) / 4, 256, 0, stream>>>(features, XH, M);

    const int gblk = Mp / 128;  // 782

    // layer 1: X[Mp,256] @ W0 -> T[Mp,128] ; spmm+relu -> H[Mp,128] (bf16, in XH)
    gemm_bf16_mfma<128, 2, 2><<<gblk, 256, 0, stream>>>(XH, W0T, T, IN_DIM);
    spmm_bf16<128, true, false><<<(M + 15) / 16, 256, 0, stream>>>(rowptr, pairs, T, XH, M);

    // layer 2: H[Mp,128] @ W1 -> T[Mp,64] ; spmm+relu -> H[Mp,64]
    gemm_bf16_mfma<64, 2, 2><<<gblk, 256, 0, stream>>>(XH, W1T, T, HD1);
    spmm_bf16<64, true, false><<<(M + 31) / 32, 256, 0, stream>>>(rowptr, pairs, T, XH, M);

    // layer 3: H[Mp,64] @ W2 -> T[Mp,32] ; spmm -> out (fp32)
    gemm_bf16_mfma<32, 4, 1><<<gblk, 256, 0, stream>>>(XH, W2T, T, HD2);
    spmm_bf16<32, false, true><<<(M + 63) / 64, 256, 0, stream>>>(rowptr, pairs, T, out, M);
}

// Round 12
// 413.340 us; speedup vs baseline: 1.2380x; 1.2380x over previous
//
#include <hip/hip_runtime.h>

// GCN forward: l2norm -> [GEMM -> SpMM -> ReLU] x3 (last layer no ReLU)
// CSR built on-device with a two-level bucket build using LDS atomics ONLY
// (random device-scope global atomics are rate-limited at ~24 ops/ns on MI355X
// and write through L2 at 32B/op — measured r11: hist 67us, 50MB writes).
// GEMMs on bf16 MFMA (16x16x32, fp32 accum), global_load_lds staging with
// pre-swizzled source. X, H, T, W bf16; SpMM accumulates fp32; output fp32.

constexpr int IN_DIM = 256, HD1 = 128, HD2 = 64, OUT_DIM = 32;
constexpr int P1B = 256;  // blocks in bucket_count / bucket_place

typedef __bf16 bf16x8 __attribute__((ext_vector_type(8)));
typedef float f32x4 __attribute__((ext_vector_type(4)));

__device__ inline ushort f32_to_bf16(float x) {
    unsigned u = __float_as_uint(x);
    unsigned r = (u + 0x7fff + ((u >> 16) & 1)) >> 16;  // round-nearest-even
    return (ushort)r;
}

__device__ inline void unpack_bf16x2(unsigned u, float& lo, float& hi) {
    lo = __uint_as_float(u << 16);
    hi = __uint_as_float(u & 0xffff0000u);
}

// ---------------- L2 normalize -> bf16 X (one wave per row) ----------------
__global__ __launch_bounds__(256) void l2norm_kernel(const float* __restrict__ in,
                                                     ushort* __restrict__ out, int M) {
    int wave = threadIdx.x >> 6;
    int lane = threadIdx.x & 63;
    int row = blockIdx.x * 4 + wave;
    if (row >= M) return;
    const float4 v = *reinterpret_cast<const float4*>(&in[(size_t)row * IN_DIM + lane * 4]);
    float s = v.x * v.x + v.y * v.y + v.z * v.z + v.w * v.w;
    #pragma unroll
    for (int off = 32; off; off >>= 1) s += __shfl_xor(s, off, 64);
    float scale = 1.0f / sqrtf(fmaxf(s, 1e-12f));
    uint2 pk;
    pk.x = (unsigned)f32_to_bf16(v.x * scale) | ((unsigned)f32_to_bf16(v.y * scale) << 16);
    pk.y = (unsigned)f32_to_bf16(v.z * scale) | ((unsigned)f32_to_bf16(v.w * scale) << 16);
    *reinterpret_cast<uint2*>(&out[(size_t)row * IN_DIM + lane * 4]) = pk;
}

// ---------------- weight transpose + bf16: WT[n][k] = W[k][n] ----------------
__global__ __launch_bounds__(256) void wt_kernel(const float* __restrict__ W,
                                                 ushort* __restrict__ WT, int K, int N) {
    int idx = blockIdx.x * 256 + threadIdx.x;
    if (idx < K * N) {
        int k = idx / N, n = idx % N;
        WT[(size_t)n * K + k] = f32_to_bf16(W[idx]);
    }
}

// ================= bucket CSR build (LDS atomics only) =================
// bucket b = row >> 8 (256 rows per bucket).

// P1a: per-block bucket histogram (LDS), write blockcnt[b*P1B + blk]
__global__ __launch_bounds__(256) void bucket_count(const int* __restrict__ row,
                                                    int* __restrict__ blockcnt,
                                                    int E, int nbuk, int epb) {
    __shared__ int cnt[512];
    for (int i = threadIdx.x; i < nbuk; i += 256) cnt[i] = 0;
    __syncthreads();
    const int base = blockIdx.x * epb;
    const int end = min(E, base + epb);
    for (int e = base + threadIdx.x; e < end; e += 256)
        atomicAdd(&cnt[row[e] >> 8], 1);
    __syncthreads();
    for (int i = threadIdx.x; i < nbuk; i += 256)
        blockcnt[i * P1B + blockIdx.x] = cnt[i];
}

// P1s: per-bucket exclusive scan over blocks -> blockoff; bucket totals
__global__ __launch_bounds__(256) void scan_bucket_blocks(const int* __restrict__ blockcnt,
                                                          int* __restrict__ blockoff,
                                                          int* __restrict__ bucketcnt) {
    __shared__ int sm[256];
    const int b = blockIdx.x, tid = threadIdx.x;
    const int v = blockcnt[b * P1B + tid];
    sm[tid] = v;
    __syncthreads();
    #pragma unroll
    for (int off = 1; off < 256; off <<= 1) {
        int t = (tid >= off) ? sm[tid - off] : 0;
        __syncthreads();
        sm[tid] += t;
        __syncthreads();
    }
    blockoff[b * P1B + tid] = sm[tid] - v;
    if (tid == 255) bucketcnt[b] = sm[255];
}

// P1s2: exclusive scan of bucket totals -> bucket_base[0..nbuk]
__global__ __launch_bounds__(512) void scan_bucket_base(const int* __restrict__ bucketcnt,
                                                        int* __restrict__ bucket_base, int nbuk) {
    __shared__ int sm[512];
    const int tid = threadIdx.x;
    const int v = (tid < nbuk) ? bucketcnt[tid] : 0;
    sm[tid] = v;
    __syncthreads();
    #pragma unroll
    for (int off = 1; off < 512; off <<= 1) {
        int t = (tid >= off) ? sm[tid - off] : 0;
        __syncthreads();
        sm[tid] += t;
        __syncthreads();
    }
    if (tid < nbuk) bucket_base[tid] = sm[tid] - v;
    if (tid == 511) bucket_base[nbuk] = sm[511];
}

// P1b: place edges into reserved per-block slices of bucket regions.
// ebuf.x = col(17b) | rlow(8b)<<17 ; ebuf.y = val bits
__global__ __launch_bounds__(256) void bucket_place(const int* __restrict__ row,
                                                    const int* __restrict__ col,
                                                    const float* __restrict__ val,
                                                    const int* __restrict__ blockoff,
                                                    const int* __restrict__ bucket_base,
                                                    int2* __restrict__ ebuf,
                                                    int E, int nbuk, int epb) {
    __shared__ int pos[512];
    for (int i = threadIdx.x; i < nbuk; i += 256)
        pos[i] = bucket_base[i] + blockoff[i * P1B + blockIdx.x];
    __syncthreads();
    const int base = blockIdx.x * epb;
    const int end = min(E, base + epb);
    for (int e = base + threadIdx.x; e < end; e += 256) {
        int r = row[e];
        int b = r >> 8;
        int p = atomicAdd(&pos[b], 1);
        ebuf[p] = make_int2(col[e] | ((r & 255) << 17), __float_as_int(val[e]));
    }
}

// P2: one block per bucket: LDS hist over 256 local rows, LDS scan -> row_ptr,
// LDS-cursor scatter into final CSR pairs (bucket region is L2-resident).
__global__ __launch_bounds__(256) void bucket_csr(const int2* __restrict__ ebuf,
                                                  const int* __restrict__ bucket_base,
                                                  int2* __restrict__ pairs,
                                                  int* __restrict__ row_ptr,
                                                  int M, int nbuk) {
    __shared__ int cnt[256];
    __shared__ int pos[256];
    const int b = blockIdx.x, tid = threadIdx.x;
    const int start = bucket_base[b], end = bucket_base[b + 1];
    cnt[tid] = 0;
    __syncthreads();
    for (int j = start + tid; j < end; j += 256)
        atomicAdd(&cnt[(ebuf[j].x >> 17) & 255], 1);
    __syncthreads();
    const int v = cnt[tid];
    pos[tid] = v;
    __syncthreads();
    #pragma unroll
    for (int off = 1; off < 256; off <<= 1) {
        int t = (tid >= off) ? pos[tid - off] : 0;
        __syncthreads();
        pos[tid] += t;
        __syncthreads();
    }
    const int excl = pos[tid] - v;
    const int rg = b * 256 + tid;
    if (rg < M) row_ptr[rg] = start + excl;
    if (rg == M) row_ptr[M] = start + excl;   // first padded row: = E
    __syncthreads();
    cnt[tid] = excl;  // reuse as cursor
    __syncthreads();
    for (int j = start + tid; j < end; j += 256) {
        int2 e = ebuf[j];
        int rlow = (e.x >> 17) & 255;
        int p = atomicAdd(&cnt[rlow], 1);
        pairs[start + p] = make_int2(e.x & 0x1FFFF, e.y);
    }
}

// ---------------- bf16 MFMA GEMM: C[Mp,BN] = A[Mp,K] @ BT[BN,K]^T ----------------
// BM=128 rows/block, BK=64, 4 waves (WM x WN). LDS rows are 128B (64 bf16) with
// XOR swizzle ((row&7)<<4) applied on the GLOBAL source (staging) and on ds_read.
template <int BN, int WM, int WN>
__global__ __launch_bounds__(256) void gemm_bf16_mfma(
    const ushort* __restrict__ A, const ushort* __restrict__ BT,
    ushort* __restrict__ C, int K) {
    constexpr int BM = 128, BK = 64;
    constexpr int FM = BM / WM / 16;
    constexpr int FN = BN / WN / 16;
    __shared__ ushort As[BM * BK];
    __shared__ ushort Bs[BN * BK];
    const int tid = threadIdx.x;
    const int lane = tid & 63;
    const int wid = tid >> 6;
    const int wm = wid / WN;
    const int wn = wid % WN;
    const int row0 = blockIdx.x * BM;
    const size_t strideB = (size_t)K * 2;  // bytes per row of A and BT

    f32x4 acc[FM][FN] = {};

    // reader lane offset within a 16-row x 64-col subtile (bytes), swizzled
    const int lkb = ((lane >> 4) << 4) ^ ((lane & 7) << 4);
    const int laneOff = (lane & 15) * 128 + lkb;

    for (int k0 = 0; k0 < K; k0 += BK) {
        // ---- stage A tile (BM rows) ----
        {
            constexpr int per_wave = BM * 128 / 4;
            const char* gbase = (const char*)(A + (size_t)row0 * K);
            #pragma unroll
            for (int i = 0; i < per_wave / 1024; ++i) {
                int o = wid * per_wave + i * 1024 + lane * 16;
                int row = o >> 7;
                int kb = (o & 127) ^ ((row & 7) << 4);
                const char* src = gbase + (size_t)row * strideB + (size_t)k0 * 2 + kb;
                ushort* dst = As + (wid * per_wave + i * 1024) / 2;
                __builtin_amdgcn_global_load_lds(
                    (const __attribute__((address_space(1))) unsigned int*)src,
                    (__attribute__((address_space(3))) unsigned int*)dst, 16, 0, 0);
            }
        }
        // ---- stage B tile (BN rows) ----
        {
            constexpr int per_wave = BN * 128 / 4;
            const char* gbase = (const char*)BT;
            #pragma unroll
            for (int i = 0; i < per_wave / 1024; ++i) {
                int o = wid * per_wave + i * 1024 + lane * 16;
                int row = o >> 7;
                int kb = (o & 127) ^ ((row & 7) << 4);
                const char* src = gbase + (size_t)row * strideB + (size_t)k0 * 2 + kb;
                ushort* dst = Bs + (wid * per_wave + i * 1024) / 2;
                __builtin_amdgcn_global_load_lds(
                    (const __attribute__((address_space(1))) unsigned int*)src,
                    (__attribute__((address_space(3))) unsigned int*)dst, 16, 0, 0);
            }
        }
        __syncthreads();

        #pragma unroll
        for (int w = 0; w < BK / 32; ++w) {
            bf16x8 af[FM], bfr[FN];
            #pragma unroll
            for (int mi = 0; mi < FM; ++mi) {
                int byte = wm * FM * 2048 + mi * 2048 + (laneOff ^ (w << 6));
                af[mi] = *(const bf16x8*)((const char*)As + byte);
            }
            #pragma unroll
            for (int ni = 0; ni < FN; ++ni) {
                int byte = wn * FN * 2048 + ni * 2048 + (laneOff ^ (w << 6));
                bfr[ni] = *(const bf16x8*)((const char*)Bs + byte);
            }
            #pragma unroll
            for (int mi = 0; mi < FM; ++mi)
                #pragma unroll
                for (int ni = 0; ni < FN; ++ni)
                    acc[mi][ni] = __builtin_amdgcn_mfma_f32_16x16x32_bf16(
                        af[mi], bfr[ni], acc[mi][ni], 0, 0, 0);
        }
        __syncthreads();
    }

    // ---- store C (bf16), C/D layout: col=lane&15, row=(lane>>4)*4+r ----
    #pragma unroll
    for (int mi = 0; mi < FM; ++mi) {
        #pragma unroll
        for (int ni = 0; ni < FN; ++ni) {
            int rbase = row0 + wm * FM * 16 + mi * 16 + ((lane >> 4) << 2);
            int col = wn * FN * 16 + ni * 16 + (lane & 15);
            #pragma unroll
            for (int r = 0; r < 4; ++r)
                C[(size_t)(rbase + r) * BN + col] = f32_to_bf16(acc[mi][ni][r]);
        }
    }
}

// ---------------- CSR SpMM, bf16 gather: out[r,:] = sum_j val_j * H[col_j,:] ----------------
template <int D, bool RELU, bool OUTF32>
__global__ __launch_bounds__(256) void spmm_bf16(const int* __restrict__ row_ptr,
                                                 const int2* __restrict__ pairs,
                                                 const ushort* __restrict__ H,
                                                 void* __restrict__ outp, int M) {
    constexpr int TPR = D / 8;                 // threads per row, 8 bf16 (16B) per lane
    const int rpb = 256 / TPR;
    const int lg = threadIdx.x % TPR;
    const int rloc = threadIdx.x / TPR;
    int r = blockIdx.x * rpb + rloc;
    if (r >= M) return;
    const int jb = row_ptr[r], je = row_ptr[r + 1];
    float acc[8] = {};
    int j = jb;
    for (; j + 1 < je; j += 2) {               // two independent gathers in flight
        int2 p0 = pairs[j];
        int2 p1 = pairs[j + 1];
        uint4 u0 = *reinterpret_cast<const uint4*>(&H[(size_t)p0.x * D + lg * 8]);
        uint4 u1 = *reinterpret_cast<const uint4*>(&H[(size_t)p1.x * D + lg * 8]);
        float v0 = __int_as_float(p0.y), v1 = __int_as_float(p1.y);
        float f[8];
        unpack_bf16x2(u0.x, f[0], f[1]); unpack_bf16x2(u0.y, f[2], f[3]);
        unpack_bf16x2(u0.z, f[4], f[5]); unpack_bf16x2(u0.w, f[6], f[7]);
        #pragma unroll
        for (int i = 0; i < 8; ++i) acc[i] = fmaf(v0, f[i], acc[i]);
        unpack_bf16x2(u1.x, f[0], f[1]); unpack_bf16x2(u1.y, f[2], f[3]);
        unpack_bf16x2(u1.z, f[4], f[5]); unpack_bf16x2(u1.w, f[6], f[7]);
        #pragma unroll
        for (int i = 0; i < 8; ++i) acc[i] = fmaf(v1, f[i], acc[i]);
    }
    if (j < je) {
        int2 p0 = pairs[j];
        uint4 u0 = *reinterpret_cast<const uint4*>(&H[(size_t)p0.x * D + lg * 8]);
        float v0 = __int_as_float(p0.y);
        float f[8];
        unpack_bf16x2(u0.x, f[0], f[1]); unpack_bf16x2(u0.y, f[2], f[3]);
        unpack_bf16x2(u0.z, f[4], f[5]); unpack_bf16x2(u0.w, f[6], f[7]);
        #pragma unroll
        for (int i = 0; i < 8; ++i) acc[i] = fmaf(v0, f[i], acc[i]);
    }
    if (RELU) {
        #pragma unroll
        for (int i = 0; i < 8; ++i) acc[i] = fmaxf(acc[i], 0.f);
    }
    if (OUTF32) {
        float* dst = (float*)outp + (size_t)r * D + lg * 8;
        *reinterpret_cast<float4*>(dst) = *reinterpret_cast<const float4*>(&acc[0]);
        *reinterpret_cast<float4*>(dst + 4) = *reinterpret_cast<const float4*>(&acc[4]);
    } else {
        uint4 pk;
        pk.x = (unsigned)f32_to_bf16(acc[0]) | ((unsigned)f32_to_bf16(acc[1]) << 16);
        pk.y = (unsigned)f32_to_bf16(acc[2]) | ((unsigned)f32_to_bf16(acc[3]) << 16);
        pk.z = (unsigned)f32_to_bf16(acc[4]) | ((unsigned)f32_to_bf16(acc[5]) << 16);
        pk.w = (unsigned)f32_to_bf16(acc[6]) | ((unsigned)f32_to_bf16(acc[7]) << 16);
        *reinterpret_cast<uint4*>((ushort*)outp + (size_t)r * D + lg * 8) = pk;
    }
}

extern "C" void kernel_launch(void* const* d_in, const int* in_sizes, int n_in,
                              void* d_out, int out_size, void* d_ws, size_t ws_size,
                              hipStream_t stream) {
    const float* features  = (const float*)d_in[0];
    const float* edge_vals = (const float*)d_in[1];
    const float* W0        = (const float*)d_in[2];
    const float* W1        = (const float*)d_in[3];
    const float* W2        = (const float*)d_in[4];
    const int*   edge_row  = (const int*)d_in[5];
    const int*   edge_col  = (const int*)d_in[6];
    const int M = in_sizes[0] / IN_DIM;     // 100000
    const int E = in_sizes[1];              // 1600000
    const int Mp = ((M + 127) / 128) * 128; // 100096, padded for GEMM tiles
    const int nbuk = (M + 255) >> 8;        // 391 buckets of 256 rows
    const int epb = (E + P1B - 1) / P1B;    // edges per bucket-build block

    char* ws = (char*)d_ws;
    size_t o = 0;
    auto alloc = [&](size_t bytes) {
        size_t r = o;
        o += (bytes + 1023) & ~(size_t)1023;
        return r;
    };
    ushort* XH      = (ushort*)(ws + alloc((size_t)Mp * IN_DIM * 2));  // X, then reused as H
    ushort* T       = (ushort*)(ws + alloc((size_t)Mp * HD1 * 2));     // GEMM outputs (bf16)
    int*   rowptr   = (int*)(ws + alloc((size_t)(M + 2) * 4));
    int2*  pairs    = (int2*)(ws + alloc((size_t)E * 8));
    int2*  ebuf     = (int2*)(ws + alloc((size_t)E * 8));
    int*   blockcnt = (int*)(ws + alloc((size_t)512 * P1B * 4));
    int*   blockoff = (int*)(ws + alloc((size_t)512 * P1B * 4));
    int*   bucketcnt= (int*)(ws + alloc((size_t)512 * 4));
    int*   bucketbase=(int*)(ws + alloc((size_t)513 * 4));
    ushort* W0T     = (ushort*)(ws + alloc((size_t)HD1 * IN_DIM * 2));
    ushort* W1T     = (ushort*)(ws + alloc((size_t)HD2 * HD1 * 2));
    ushort* W2T     = (ushort*)(ws + alloc((size_t)OUT_DIM * HD2 * 2));
    float* out = (float*)d_out;
    (void)ws_size; (void)n_in; (void)out_size;

    // CSR build — LDS atomics only, no global memset needed
    bucket_count<<<P1B, 256, 0, stream>>>(edge_row, blockcnt, E, nbuk, epb);
    scan_bucket_blocks<<<nbuk, 256, 0, stream>>>(blockcnt, blockoff, bucketcnt);
    scan_bucket_base<<<1, 512, 0, stream>>>(bucketcnt, bucketbase, nbuk);
    bucket_place<<<P1B, 256, 0, stream>>>(edge_row, edge_col, edge_vals,
                                          blockoff, bucketbase, ebuf, E, nbuk, epb);
    bucket_csr<<<nbuk, 256, 0, stream>>>(ebuf, bucketbase, pairs, rowptr, M, nbuk);

    // weights -> bf16 transposed
    wt_kernel<<<(IN_DIM * HD1 + 255) / 256, 256, 0, stream>>>(W0, W0T, IN_DIM, HD1);
    wt_kernel<<<(HD1 * HD2 + 255) / 256, 256, 0, stream>>>(W1, W1T, HD1, HD2);
    wt_kernel<<<(HD2 * OUT_DIM + 255) / 256, 256, 0, stream>>>(W2, W2T, HD2, OUT_DIM);

    // normalize -> bf16 X
    l2norm_kernel<<<(M + 3) / 4, 256, 0, stream>>>(features, XH, M);

    const int gblk = Mp / 128;  // 782

    // layer 1: X[Mp,256] @ W0 -> T[Mp,128] ; spmm+relu -> H[Mp,128] (bf16, in XH)
    gemm_bf16_mfma<128, 2, 2><<<gblk, 256, 0, stream>>>(XH, W0T, T, IN_DIM);
    spmm_bf16<128, true, false><<<(M + 15) / 16, 256, 0, stream>>>(rowptr, pairs, T, XH, M);

    // layer 2: H[Mp,128] @ W1 -> T[Mp,64] ; spmm+relu -> H[Mp,64]
    gemm_bf16_mfma<64, 2, 2><<<gblk, 256, 0, stream>>>(XH, W1T, T, HD1);
    spmm_bf16<64, true, false><<<(M + 31) / 32, 256, 0, stream>>>(rowptr, pairs, T, XH, M);

    // layer 3: H[Mp,64] @ W2 -> T[Mp,32] ; spmm -> out (fp32)
    gemm_bf16_mfma<32, 4, 1><<<gblk, 256, 0, stream>>>(XH, W2T, T, HD2);
    spmm_bf16<32, false, true><<<(M + 63) / 64, 256, 0, stream>>>(rowptr, pairs, T, out, M);
}

// Round 13
// 409.830 us; speedup vs baseline: 1.2486x; 1.0086x over previous
//
#include <hip/hip_runtime.h>

// GCN forward: l2norm -> [GEMM -> SpMM -> ReLU] x3 (last layer no ReLU)
// CSR via two-level bucket build (LDS atomics only).
// SpMM: wave-per-row, EPW edges in flight per wave, shfl_xor tree reduce
// (kills inter-row lockstep divergence; raises outstanding gathers).
// GEMMs on bf16 MFMA (16x16x32, fp32 accum), global_load_lds staging with
// pre-swizzled source. X, H, T, W bf16; SpMM accumulates fp32; output fp32.

constexpr int IN_DIM = 256, HD1 = 128, HD2 = 64, OUT_DIM = 32;
constexpr int P1B = 256;  // blocks in bucket_count / bucket_place

typedef __bf16 bf16x8 __attribute__((ext_vector_type(8)));
typedef float f32x4 __attribute__((ext_vector_type(4)));

__device__ inline ushort f32_to_bf16(float x) {
    unsigned u = __float_as_uint(x);
    unsigned r = (u + 0x7fff + ((u >> 16) & 1)) >> 16;  // round-nearest-even
    return (ushort)r;
}

__device__ inline void unpack_bf16x2(unsigned u, float& lo, float& hi) {
    lo = __uint_as_float(u << 16);
    hi = __uint_as_float(u & 0xffff0000u);
}

// ---------------- L2 normalize -> bf16 X (one wave per row) ----------------
__global__ __launch_bounds__(256) void l2norm_kernel(const float* __restrict__ in,
                                                     ushort* __restrict__ out, int M) {
    int wave = threadIdx.x >> 6;
    int lane = threadIdx.x & 63;
    int row = blockIdx.x * 4 + wave;
    if (row >= M) return;
    const float4 v = *reinterpret_cast<const float4*>(&in[(size_t)row * IN_DIM + lane * 4]);
    float s = v.x * v.x + v.y * v.y + v.z * v.z + v.w * v.w;
    #pragma unroll
    for (int off = 32; off; off >>= 1) s += __shfl_xor(s, off, 64);
    float scale = 1.0f / sqrtf(fmaxf(s, 1e-12f));
    uint2 pk;
    pk.x = (unsigned)f32_to_bf16(v.x * scale) | ((unsigned)f32_to_bf16(v.y * scale) << 16);
    pk.y = (unsigned)f32_to_bf16(v.z * scale) | ((unsigned)f32_to_bf16(v.w * scale) << 16);
    *reinterpret_cast<uint2*>(&out[(size_t)row * IN_DIM + lane * 4]) = pk;
}

// ---------------- all weights -> bf16 transposed, one launch ----------------
__global__ __launch_bounds__(256) void wt_all(const float* __restrict__ W0,
                                              const float* __restrict__ W1,
                                              const float* __restrict__ W2,
                                              ushort* __restrict__ W0T,
                                              ushort* __restrict__ W1T,
                                              ushort* __restrict__ W2T) {
    int idx = blockIdx.x * 256 + threadIdx.x;
    if (idx < IN_DIM * HD1) {
        int k = idx / HD1, n = idx % HD1;
        W0T[(size_t)n * IN_DIM + k] = f32_to_bf16(W0[idx]);
    } else if (idx < IN_DIM * HD1 + HD1 * HD2) {
        int i = idx - IN_DIM * HD1;
        int k = i / HD2, n = i % HD2;
        W1T[(size_t)n * HD1 + k] = f32_to_bf16(W1[i]);
    } else if (idx < IN_DIM * HD1 + HD1 * HD2 + HD2 * OUT_DIM) {
        int i = idx - IN_DIM * HD1 - HD1 * HD2;
        int k = i / OUT_DIM, n = i % OUT_DIM;
        W2T[(size_t)n * HD2 + k] = f32_to_bf16(W2[i]);
    }
}

// ================= bucket CSR build (LDS atomics only) =================
// bucket b = row >> 8 (256 rows per bucket).

__global__ __launch_bounds__(256) void bucket_count(const int* __restrict__ row,
                                                    int* __restrict__ blockcnt,
                                                    int E, int nbuk, int epb) {
    __shared__ int cnt[512];
    for (int i = threadIdx.x; i < nbuk; i += 256) cnt[i] = 0;
    __syncthreads();
    const int base = blockIdx.x * epb;
    const int end = min(E, base + epb);
    for (int e = base + threadIdx.x; e < end; e += 256)
        atomicAdd(&cnt[row[e] >> 8], 1);
    __syncthreads();
    for (int i = threadIdx.x; i < nbuk; i += 256)
        blockcnt[i * P1B + blockIdx.x] = cnt[i];
}

__global__ __launch_bounds__(256) void scan_bucket_blocks(const int* __restrict__ blockcnt,
                                                          int* __restrict__ blockoff,
                                                          int* __restrict__ bucketcnt) {
    __shared__ int sm[256];
    const int b = blockIdx.x, tid = threadIdx.x;
    const int v = blockcnt[b * P1B + tid];
    sm[tid] = v;
    __syncthreads();
    #pragma unroll
    for (int off = 1; off < 256; off <<= 1) {
        int t = (tid >= off) ? sm[tid - off] : 0;
        __syncthreads();
        sm[tid] += t;
        __syncthreads();
    }
    blockoff[b * P1B + tid] = sm[tid] - v;
    if (tid == 255) bucketcnt[b] = sm[255];
}

__global__ __launch_bounds__(512) void scan_bucket_base(const int* __restrict__ bucketcnt,
                                                        int* __restrict__ bucket_base, int nbuk) {
    __shared__ int sm[512];
    const int tid = threadIdx.x;
    const int v = (tid < nbuk) ? bucketcnt[tid] : 0;
    sm[tid] = v;
    __syncthreads();
    #pragma unroll
    for (int off = 1; off < 512; off <<= 1) {
        int t = (tid >= off) ? sm[tid - off] : 0;
        __syncthreads();
        sm[tid] += t;
        __syncthreads();
    }
    if (tid < nbuk) bucket_base[tid] = sm[tid] - v;
    if (tid == 511) bucket_base[nbuk] = sm[511];
}

// ebuf.x = col(17b) | rlow(8b)<<17 ; ebuf.y = val bits
__global__ __launch_bounds__(256) void bucket_place(const int* __restrict__ row,
                                                    const int* __restrict__ col,
                                                    const float* __restrict__ val,
                                                    const int* __restrict__ blockoff,
                                                    const int* __restrict__ bucket_base,
                                                    int2* __restrict__ ebuf,
                                                    int E, int nbuk, int epb) {
    __shared__ int pos[512];
    for (int i = threadIdx.x; i < nbuk; i += 256)
        pos[i] = bucket_base[i] + blockoff[i * P1B + blockIdx.x];
    __syncthreads();
    const int base = blockIdx.x * epb;
    const int end = min(E, base + epb);
    for (int e = base + threadIdx.x; e < end; e += 256) {
        int r = row[e];
        int b = r >> 8;
        int p = atomicAdd(&pos[b], 1);
        ebuf[p] = make_int2(col[e] | ((r & 255) << 17), __float_as_int(val[e]));
    }
}

__global__ __launch_bounds__(256) void bucket_csr(const int2* __restrict__ ebuf,
                                                  const int* __restrict__ bucket_base,
                                                  int2* __restrict__ pairs,
                                                  int* __restrict__ row_ptr,
                                                  int M, int nbuk) {
    __shared__ int cnt[256];
    __shared__ int pos[256];
    const int b = blockIdx.x, tid = threadIdx.x;
    const int start = bucket_base[b], end = bucket_base[b + 1];
    cnt[tid] = 0;
    __syncthreads();
    for (int j = start + tid; j < end; j += 256)
        atomicAdd(&cnt[(ebuf[j].x >> 17) & 255], 1);
    __syncthreads();
    const int v = cnt[tid];
    pos[tid] = v;
    __syncthreads();
    #pragma unroll
    for (int off = 1; off < 256; off <<= 1) {
        int t = (tid >= off) ? pos[tid - off] : 0;
        __syncthreads();
        pos[tid] += t;
        __syncthreads();
    }
    const int excl = pos[tid] - v;
    const int rg = b * 256 + tid;
    if (rg < M) row_ptr[rg] = start + excl;
    if (rg == M) row_ptr[M] = start + excl;   // = E
    __syncthreads();
    cnt[tid] = excl;  // reuse as cursor
    __syncthreads();
    for (int j = start + tid; j < end; j += 256) {
        int2 e = ebuf[j];
        int rlow = (e.x >> 17) & 255;
        int p = atomicAdd(&cnt[rlow], 1);
        pairs[start + p] = make_int2(e.x & 0x1FFFF, e.y);
    }
}

// ---------------- bf16 MFMA GEMM: C[Mp,BN] = A[Mp,K] @ BT[BN,K]^T ----------------
template <int BN, int WM, int WN>
__global__ __launch_bounds__(256) void gemm_bf16_mfma(
    const ushort* __restrict__ A, const ushort* __restrict__ BT,
    ushort* __restrict__ C, int K) {
    constexpr int BM = 128, BK = 64;
    constexpr int FM = BM / WM / 16;
    constexpr int FN = BN / WN / 16;
    __shared__ ushort As[BM * BK];
    __shared__ ushort Bs[BN * BK];
    const int tid = threadIdx.x;
    const int lane = tid & 63;
    const int wid = tid >> 6;
    const int wm = wid / WN;
    const int wn = wid % WN;
    const int row0 = blockIdx.x * BM;
    const size_t strideB = (size_t)K * 2;

    f32x4 acc[FM][FN] = {};

    const int lkb = ((lane >> 4) << 4) ^ ((lane & 7) << 4);
    const int laneOff = (lane & 15) * 128 + lkb;

    for (int k0 = 0; k0 < K; k0 += BK) {
        {
            constexpr int per_wave = BM * 128 / 4;
            const char* gbase = (const char*)(A + (size_t)row0 * K);
            #pragma unroll
            for (int i = 0; i < per_wave / 1024; ++i) {
                int o = wid * per_wave + i * 1024 + lane * 16;
                int row = o >> 7;
                int kb = (o & 127) ^ ((row & 7) << 4);
                const char* src = gbase + (size_t)row * strideB + (size_t)k0 * 2 + kb;
                ushort* dst = As + (wid * per_wave + i * 1024) / 2;
                __builtin_amdgcn_global_load_lds(
                    (const __attribute__((address_space(1))) unsigned int*)src,
                    (__attribute__((address_space(3))) unsigned int*)dst, 16, 0, 0);
            }
        }
        {
            constexpr int per_wave = BN * 128 / 4;
            const char* gbase = (const char*)BT;
            #pragma unroll
            for (int i = 0; i < per_wave / 1024; ++i) {
                int o = wid * per_wave + i * 1024 + lane * 16;
                int row = o >> 7;
                int kb = (o & 127) ^ ((row & 7) << 4);
                const char* src = gbase + (size_t)row * strideB + (size_t)k0 * 2 + kb;
                ushort* dst = Bs + (wid * per_wave + i * 1024) / 2;
                __builtin_amdgcn_global_load_lds(
                    (const __attribute__((address_space(1))) unsigned int*)src,
                    (__attribute__((address_space(3))) unsigned int*)dst, 16, 0, 0);
            }
        }
        __syncthreads();

        #pragma unroll
        for (int w = 0; w < BK / 32; ++w) {
            bf16x8 af[FM], bfr[FN];
            #pragma unroll
            for (int mi = 0; mi < FM; ++mi) {
                int byte = wm * FM * 2048 + mi * 2048 + (laneOff ^ (w << 6));
                af[mi] = *(const bf16x8*)((const char*)As + byte);
            }
            #pragma unroll
            for (int ni = 0; ni < FN; ++ni) {
                int byte = wn * FN * 2048 + ni * 2048 + (laneOff ^ (w << 6));
                bfr[ni] = *(const bf16x8*)((const char*)Bs + byte);
            }
            #pragma unroll
            for (int mi = 0; mi < FM; ++mi)
                #pragma unroll
                for (int ni = 0; ni < FN; ++ni)
                    acc[mi][ni] = __builtin_amdgcn_mfma_f32_16x16x32_bf16(
                        af[mi], bfr[ni], acc[mi][ni], 0, 0, 0);
        }
        __syncthreads();
    }

    #pragma unroll
    for (int mi = 0; mi < FM; ++mi) {
        #pragma unroll
        for (int ni = 0; ni < FN; ++ni) {
            int rbase = row0 + wm * FM * 16 + mi * 16 + ((lane >> 4) << 2);
            int col = wn * FN * 16 + ni * 16 + (lane & 15);
            #pragma unroll
            for (int r = 0; r < 4; ++r)
                C[(size_t)(rbase + r) * BN + col] = f32_to_bf16(acc[mi][ni][r]);
        }
    }
}

// ---------------- SpMM: wave-per-row, EPW edges in flight ----------------
// Lanes split into EPW=64/(D/8) edge-groups; group eg gathers edge (base+eg)'s
// 16B slice; cross-group shfl_xor tree reduces at row end. x2 per-lane unroll.
template <int D, bool RELU, bool OUTF32>
__global__ __launch_bounds__(256) void spmm_wave(const int* __restrict__ row_ptr,
                                                 const int2* __restrict__ pairs,
                                                 const ushort* __restrict__ H,
                                                 void* __restrict__ outp, int M) {
    constexpr int LPE = D / 8;       // lanes per edge (16B each)
    constexpr int EPW = 64 / LPE;    // edge groups per wave
    const int wv = threadIdx.x >> 6;
    const int lane = threadIdx.x & 63;
    const int eg = lane / LPE;
    const int li = lane % LPE;
    const int r = blockIdx.x * 4 + wv;
    if (r >= M) return;
    const int jb = row_ptr[r], je = row_ptr[r + 1];
    float acc[8] = {};
    for (int base = jb; base < je; base += 2 * EPW) {
        int j0 = base + eg, j1 = base + EPW + eg;
        int2 p0 = pairs[min(j0, je - 1)];
        int2 p1 = pairs[min(j1, je - 1)];
        float v0 = (j0 < je) ? __int_as_float(p0.y) : 0.f;
        float v1 = (j1 < je) ? __int_as_float(p1.y) : 0.f;
        uint4 u0 = *reinterpret_cast<const uint4*>(&H[(size_t)p0.x * D + li * 8]);
        uint4 u1 = *reinterpret_cast<const uint4*>(&H[(size_t)p1.x * D + li * 8]);
        float f[8];
        unpack_bf16x2(u0.x, f[0], f[1]); unpack_bf16x2(u0.y, f[2], f[3]);
        unpack_bf16x2(u0.z, f[4], f[5]); unpack_bf16x2(u0.w, f[6], f[7]);
        #pragma unroll
        for (int i = 0; i < 8; ++i) acc[i] = fmaf(v0, f[i], acc[i]);
        unpack_bf16x2(u1.x, f[0], f[1]); unpack_bf16x2(u1.y, f[2], f[3]);
        unpack_bf16x2(u1.z, f[4], f[5]); unpack_bf16x2(u1.w, f[6], f[7]);
        #pragma unroll
        for (int i = 0; i < 8; ++i) acc[i] = fmaf(v1, f[i], acc[i]);
    }
    // reduce across edge groups (preserves li)
    #pragma unroll
    for (int off = LPE; off < 64; off <<= 1)
        #pragma unroll
        for (int i = 0; i < 8; ++i) acc[i] += __shfl_xor(acc[i], off, 64);
    if (eg != 0) return;
    if (RELU) {
        #pragma unroll
        for (int i = 0; i < 8; ++i) acc[i] = fmaxf(acc[i], 0.f);
    }
    if (OUTF32) {
        float* dst = (float*)outp + (size_t)r * D + li * 8;
        *reinterpret_cast<float4*>(dst) = *reinterpret_cast<const float4*>(&acc[0]);
        *reinterpret_cast<float4*>(dst + 4) = *reinterpret_cast<const float4*>(&acc[4]);
    } else {
        uint4 pk;
        pk.x = (unsigned)f32_to_bf16(acc[0]) | ((unsigned)f32_to_bf16(acc[1]) << 16);
        pk.y = (unsigned)f32_to_bf16(acc[2]) | ((unsigned)f32_to_bf16(acc[3]) << 16);
        pk.z = (unsigned)f32_to_bf16(acc[4]) | ((unsigned)f32_to_bf16(acc[5]) << 16);
        pk.w = (unsigned)f32_to_bf16(acc[6]) | ((unsigned)f32_to_bf16(acc[7]) << 16);
        *reinterpret_cast<uint4*>((ushort*)outp + (size_t)r * D + li * 8) = pk;
    }
}

extern "C" void kernel_launch(void* const* d_in, const int* in_sizes, int n_in,
                              void* d_out, int out_size, void* d_ws, size_t ws_size,
                              hipStream_t stream) {
    const float* features  = (const float*)d_in[0];
    const float* edge_vals = (const float*)d_in[1];
    const float* W0        = (const float*)d_in[2];
    const float* W1        = (const float*)d_in[3];
    const float* W2        = (const float*)d_in[4];
    const int*   edge_row  = (const int*)d_in[5];
    const int*   edge_col  = (const int*)d_in[6];
    const int M = in_sizes[0] / IN_DIM;     // 100000
    const int E = in_sizes[1];              // 1600000
    const int Mp = ((M + 127) / 128) * 128; // 100096
    const int nbuk = (M + 255) >> 8;        // 391
    const int epb = (E + P1B - 1) / P1B;

    char* ws = (char*)d_ws;
    size_t o = 0;
    auto alloc = [&](size_t bytes) {
        size_t r = o;
        o += (bytes + 1023) & ~(size_t)1023;
        return r;
    };
    ushort* XH      = (ushort*)(ws + alloc((size_t)Mp * IN_DIM * 2));
    ushort* T       = (ushort*)(ws + alloc((size_t)Mp * HD1 * 2));
    int*   rowptr   = (int*)(ws + alloc((size_t)(M + 2) * 4));
    int2*  pairs    = (int2*)(ws + alloc((size_t)E * 8));
    int2*  ebuf     = (int2*)(ws + alloc((size_t)E * 8));
    int*   blockcnt = (int*)(ws + alloc((size_t)512 * P1B * 4));
    int*   blockoff = (int*)(ws + alloc((size_t)512 * P1B * 4));
    int*   bucketcnt= (int*)(ws + alloc((size_t)512 * 4));
    int*   bucketbase=(int*)(ws + alloc((size_t)513 * 4));
    ushort* W0T     = (ushort*)(ws + alloc((size_t)HD1 * IN_DIM * 2));
    ushort* W1T     = (ushort*)(ws + alloc((size_t)HD2 * HD1 * 2));
    ushort* W2T     = (ushort*)(ws + alloc((size_t)OUT_DIM * HD2 * 2));
    float* out = (float*)d_out;
    (void)ws_size; (void)n_in; (void)out_size;

    // CSR build — LDS atomics only
    bucket_count<<<P1B, 256, 0, stream>>>(edge_row, blockcnt, E, nbuk, epb);
    scan_bucket_blocks<<<nbuk, 256, 0, stream>>>(blockcnt, blockoff, bucketcnt);
    scan_bucket_base<<<1, 512, 0, stream>>>(bucketcnt, bucketbase, nbuk);
    bucket_place<<<P1B, 256, 0, stream>>>(edge_row, edge_col, edge_vals,
                                          blockoff, bucketbase, ebuf, E, nbuk, epb);
    bucket_csr<<<nbuk, 256, 0, stream>>>(ebuf, bucketbase, pairs, rowptr, M, nbuk);

    // weights -> bf16 transposed (single launch)
    wt_all<<<(IN_DIM * HD1 + HD1 * HD2 + HD2 * OUT_DIM + 255) / 256, 256, 0, stream>>>(
        W0, W1, W2, W0T, W1T, W2T);

    // normalize -> bf16 X
    l2norm_kernel<<<(M + 3) / 4, 256, 0, stream>>>(features, XH, M);

    const int gblk = Mp / 128;  // 782
    const int sblk = (M + 3) / 4;

    // layer 1
    gemm_bf16_mfma<128, 2, 2><<<gblk, 256, 0, stream>>>(XH, W0T, T, IN_DIM);
    spmm_wave<128, true, false><<<sblk, 256, 0, stream>>>(rowptr, pairs, T, XH, M);

    // layer 2
    gemm_bf16_mfma<64, 2, 2><<<gblk, 256, 0, stream>>>(XH, W1T, T, HD1);
    spmm_wave<64, true, false><<<sblk, 256, 0, stream>>>(rowptr, pairs, T, XH, M);

    // layer 3
    gemm_bf16_mfma<32, 4, 1><<<gblk, 256, 0, stream>>>(XH, W2T, T, HD2);
    spmm_wave<32, false, true><<<sblk, 256, 0, stream>>>(rowptr, pairs, T, out, M);
}